// Round 2
// baseline (219.789 us; speedup 1.0000x reference)
//
#include <hip/hip_runtime.h>

// WavUnPacking: x (8,256,128,128) f32 -> out (8,64,256,256) f32
// Channel quadrants (ll,lh,hl,hh), Haar inverse butterfly into 2x2 blocks.
//
// R3: R1 dataflow (lane = 2 input cols; 4x 8B loads, 2x 16B dense stores,
// no LDS, no barrier) + 4 tiles per wave, software-pipelined:
//   preload tile 0; per tile: issue tile i+1 loads FIRST, then butterfly,
//   then 2 dense 1 KiB wave stores of tile i.
// Loads of the next tile are in flight while the current tile's stores issue,
// so the load->compute->store chain overlaps across tiles, and per-wave fixed
// overhead (kernarg, address setup, final drain) is amortized 4x.
// Butterfly uses the reference's left-to-right association -> bit-exact.

typedef float v2f __attribute__((ext_vector_type(2)));
typedef float v4f __attribute__((ext_vector_type(4)));

__global__ __launch_bounds__(256) void wav_unpack_kernel(
    const float* __restrict__ x, float* __restrict__ out) {
    constexpr int Q = 64 * 128 * 128;        // quadrant stride = 1,048,576 floats
    constexpr int ITER = 4;

    const int t  = blockIdx.x * 256 + threadIdx.x;
    const int w2 = t & 63;                   // input col pair (2*w2, 2*w2+1)
    const int hg = (t >> 6) & 31;            // group of 4 input rows
    const int bc = t >> 11;                  // b*64 + c
    const int b  = bc >> 6;
    const int h0 = hg << 2;

    // input: chan = bc + 192*b, row h0+it, cols 2*w2..2*w2+1
    const int in0  = ((bc + 192 * b) * 128 + h0) * 128 + (w2 << 1);
    // output: chan = bc, rows 2*(h0+it), 2*(h0+it)+1, cols 4*w2..4*w2+3
    const int out0 = (bc << 16) + (h0 << 9) + (w2 << 2);

    v2f ll = __builtin_nontemporal_load((const v2f*)(x + in0));
    v2f lh = __builtin_nontemporal_load((const v2f*)(x + in0 + Q));
    v2f hl = __builtin_nontemporal_load((const v2f*)(x + in0 + 2 * Q));
    v2f hh = __builtin_nontemporal_load((const v2f*)(x + in0 + 3 * Q));

#pragma unroll
    for (int it = 0; it < ITER; ++it) {
        v2f nll, nlh, nhl, nhh;
        if (it + 1 < ITER) {                 // issue next tile's loads first
            const float* p = x + in0 + 128 * (it + 1);
            nll = __builtin_nontemporal_load((const v2f*)(p));
            nlh = __builtin_nontemporal_load((const v2f*)(p + Q));
            nhl = __builtin_nontemporal_load((const v2f*)(p + 2 * Q));
            nhh = __builtin_nontemporal_load((const v2f*)(p + 3 * Q));
        }

        // Reference association: ((ll+lh)+hl)+hh etc. -> bit-exact vs jax ref.
        v4f r0, r1;
        {
            const float a = ll.x + lh.x, c = ll.x - lh.x;
            r0.x = 0.5f * ((a + hl.x) + hh.x);   // e00
            r0.y = 0.5f * ((a - hl.x) - hh.x);   // e01
            r1.x = 0.5f * ((c + hl.x) - hh.x);   // e10
            r1.y = 0.5f * ((c - hl.x) + hh.x);   // e11
        }
        {
            const float a = ll.y + lh.y, c = ll.y - lh.y;
            r0.z = 0.5f * ((a + hl.y) + hh.y);
            r0.w = 0.5f * ((a - hl.y) - hh.y);
            r1.z = 0.5f * ((c + hl.y) - hh.y);
            r1.w = 0.5f * ((c - hl.y) + hh.y);
        }

        float* o = out + out0 + (it << 9);   // 2 output rows per tile = 512 floats
        __builtin_nontemporal_store(r0, (v4f*)(o));
        __builtin_nontemporal_store(r1, (v4f*)(o + 256));

        ll = nll; lh = nlh; hl = nhl; hh = nhh;   // dead on last iter, DCE'd
    }
}

extern "C" void kernel_launch(void* const* d_in, const int* in_sizes, int n_in,
                              void* d_out, int out_size, void* d_ws, size_t ws_size,
                              hipStream_t stream) {
    const float* x = (const float*)d_in[0];
    float* out = (float*)d_out;
    // threads = 8 b * 64 c * 32 row-groups * 64 col-pairs = 1,048,576
    constexpr int total = 8 * 64 * 32 * 64;
    constexpr int block = 256;
    wav_unpack_kernel<<<total / block, block, 0, stream>>>(x, out);
}